// Round 4
// baseline (487.997 us; speedup 1.0000x reference)
//
#include <hip/hip_runtime.h>
#include <hip/hip_bf16.h>
#include <math.h>

#define D 128
#define H 4

typedef __attribute__((ext_vector_type(8))) short bf16x8;
typedef __attribute__((ext_vector_type(4))) float f32x4;

// ---------------------------------------------------------------------------
// fp32 -> bf16 split helpers (round-to-nearest-even, manual, no lib deps)
// ---------------------------------------------------------------------------
__device__ __forceinline__ unsigned short f32_to_bf16_rne(float f) {
    union { float f; unsigned u; } c; c.f = f;
    unsigned u = c.u;
    return (unsigned short)((u + 0x7FFFu + ((u >> 16) & 1u)) >> 16);
}
__device__ __forceinline__ float bf16_to_f32(unsigned short h) {
    union { unsigned u; float f; } c; c.u = ((unsigned)h) << 16;
    return c.f;
}

// ---------------------------------------------------------------------------
// Split fp32 array into bf16 hi + bf16 residual(lo). float4-vectorized.
// ---------------------------------------------------------------------------
__global__ __launch_bounds__(256) void convert_split(
    const float* __restrict__ in, unsigned short* __restrict__ hi,
    unsigned short* __restrict__ lo, int n4)
{
    int i = blockIdx.x * blockDim.x + threadIdx.x;
    if (i >= n4) return;
    float4 v = ((const float4*)in)[i];
    ushort4 h, l;
    h.x = f32_to_bf16_rne(v.x); l.x = f32_to_bf16_rne(v.x - bf16_to_f32(h.x));
    h.y = f32_to_bf16_rne(v.y); l.y = f32_to_bf16_rne(v.y - bf16_to_f32(h.y));
    h.z = f32_to_bf16_rne(v.z); l.z = f32_to_bf16_rne(v.z - bf16_to_f32(h.z));
    h.w = f32_to_bf16_rne(v.w); l.w = f32_to_bf16_rne(v.w - bf16_to_f32(h.w));
    ((ushort4*)hi)[i] = h;
    ((ushort4*)lo)[i] = l;
}

// Split the four 128x128 weight matrices into one packed hi/lo pair.
__global__ __launch_bounds__(256) void convert_w(
    const float* __restrict__ Wq, const float* __restrict__ Wk,
    const float* __restrict__ Wv, const float* __restrict__ Wo,
    unsigned short* __restrict__ wh, unsigned short* __restrict__ wl)
{
    int i = blockIdx.x * blockDim.x + threadIdx.x;
    if (i >= D * D) return;
    const float* Ws[4] = {Wq, Wk, Wv, Wo};
#pragma unroll
    for (int m = 0; m < 4; ++m) {
        float f = Ws[m][i];
        unsigned short h = f32_to_bf16_rne(f);
        wh[m * D * D + i] = h;
        wl[m * D * D + i] = f32_to_bf16_rne(f - bf16_to_f32(h));
    }
}

// ===========================================================================
// Split-precision MFMA GEMM:  out[m,n] = (sum_k x[m,k]*W[n,k] + b[n]) * scale
// x ~ xh + xl, W ~ wh + wl (bf16); computes xh*wh + xh*wl + xl*wh in fp32
// accumulators -> ~fp32 accuracy.  Block = 4 waves; wave = 16 rows x 128 cols
// (8 n-tiles of 16x16x32 MFMA, K=128 in 4 chunks).  No LDS, no barriers:
// A frag = 8 contiguous bf16 from x row (lane&15), k-offset quad*8;
// B frag = 8 contiguous bf16 from W row (lane&15) (W is [n][k] row-major);
// D: col = lane&15, row = quad*4 + reg.
// blockIdx.y selects q/k/v weight set; out-proj uses grid.y=1 + offset base.
// ===========================================================================
__global__ __launch_bounds__(256) void gemm_mfma(
    const unsigned short* __restrict__ xh, const unsigned short* __restrict__ xl,
    const unsigned short* __restrict__ whAll, const unsigned short* __restrict__ wlAll,
    const float* __restrict__ b0, const float* __restrict__ b1,
    const float* __restrict__ b2,
    float* __restrict__ o0, float* __restrict__ o1, float* __restrict__ o2,
    float scale0, int n)
{
    const int sel = blockIdx.y;
    const float* bias = (sel == 0) ? b0 : (sel == 1 ? b1 : b2);
    float* out       = (sel == 0) ? o0 : (sel == 1 ? o1 : o2);
    const float scale = (sel == 0) ? scale0 : 1.0f;
    const unsigned short* wh = whAll + (size_t)sel * D * D;
    const unsigned short* wl = wlAll + (size_t)sel * D * D;

    const int wid  = threadIdx.x >> 6;
    const int lane = threadIdx.x & 63;
    const int quad = lane >> 4;
    const int l16  = lane & 15;
    const int m0   = blockIdx.x * 64 + wid * 16;

    int arow = m0 + l16; if (arow > n - 1) arow = n - 1;
    const unsigned short* xrh = xh + (size_t)arow * D + quad * 8;
    const unsigned short* xrl = xl + (size_t)arow * D + quad * 8;
    bf16x8 ah[4], al[4];
#pragma unroll
    for (int kc = 0; kc < 4; ++kc) {
        ah[kc] = *(const bf16x8*)(xrh + kc * 32);
        al[kc] = *(const bf16x8*)(xrl + kc * 32);
    }

    const unsigned short* wrh = wh + (size_t)l16 * D + quad * 8;
    const unsigned short* wrl = wl + (size_t)l16 * D + quad * 8;

#pragma unroll
    for (int nt = 0; nt < 8; ++nt) {
        f32x4 acc = {0.f, 0.f, 0.f, 0.f};
#pragma unroll
        for (int kc = 0; kc < 4; ++kc) {
            bf16x8 bh = *(const bf16x8*)(wrh + (size_t)nt * 16 * D + kc * 32);
            bf16x8 bl = *(const bf16x8*)(wrl + (size_t)nt * 16 * D + kc * 32);
            acc = __builtin_amdgcn_mfma_f32_16x16x32_bf16(ah[kc], bh, acc, 0, 0, 0);
            acc = __builtin_amdgcn_mfma_f32_16x16x32_bf16(al[kc], bh, acc, 0, 0, 0);
            acc = __builtin_amdgcn_mfma_f32_16x16x32_bf16(ah[kc], bl, acc, 0, 0, 0);
        }
        const int colg = nt * 16 + l16;
        const float bv = bias[colg];
#pragma unroll
        for (int r = 0; r < 4; ++r) {
            int rowg = m0 + quad * 4 + r;
            if (rowg < n) out[(size_t)rowg * D + colg] = (acc[r] + bv) * scale;
        }
    }
}

// ---------------------------------------------------------------------------
// row_start[i] = first edge index e with row[e] >= i  (row is sorted)
// ---------------------------------------------------------------------------
__global__ void build_row_start(const int* __restrict__ row,
                                int* __restrict__ row_start, int n, int e)
{
    int i = blockIdx.x * blockDim.x + threadIdx.x;
    if (i > n) return;
    int lo = 0, hi = e;
    while (lo < hi) {
        int mid = (lo + hi) >> 1;
        if (row[mid] < i) lo = mid + 1; else hi = mid;
    }
    row_start[i] = lo;
}

// ===========================================================================
// Fused edge phase: SDDMM + segment-softmax + SPMM, one WAVE per node.
// (unchanged from R3 — streaming-bound at 3.8 TB/s)
// ===========================================================================
#define MAXDEG 64
#define WPB 4

__global__ __launch_bounds__(WPB * 64) void edge_attn(
    const int* __restrict__ row_start,
    const float* __restrict__ q, const float* __restrict__ k,
    const float* __restrict__ v, const int* __restrict__ col,
    float* __restrict__ y, int n)
{
    __shared__ float ssm[WPB][MAXDEG * H];
    __shared__ int   cm[WPB][MAXDEG];

    const int wid  = threadIdx.x >> 6;
    const int lane = threadIdx.x & 63;
    const int node = blockIdx.x * WPB + wid;
    if (node >= n) return;

    const int e0  = row_start[node];
    const int deg = row_start[node + 1] - e0;
    const int h   = lane & 3;
    const int dl  = deg < MAXDEG ? deg : MAXDEG;

    const float qa = q[(size_t)node * D + lane];
    const float qb = q[(size_t)node * D + lane + 64];

    for (int i = lane; i < dl; i += 64) cm[wid][i] = col[e0 + i];

    float m = -INFINITY, z = 0.f;
    float kA = 0.f, kB = 0.f;
    if (deg > 0) {
        int c0 = cm[wid][0];
        kA = k[(size_t)c0 * D + lane];
        kB = k[(size_t)c0 * D + lane + 64];
    }
    for (int e = 0; e < deg; ++e) {
        float cA = kA, cB = kB;
        if (e + 1 < deg) {
            int cn = (e + 1 < MAXDEG) ? cm[wid][e + 1] : col[e0 + e + 1];
            kA = k[(size_t)cn * D + lane];
            kB = k[(size_t)cn * D + lane + 64];
        }
        float p = qa * cA + qb * cB;
        p += __shfl_xor(p, 4);
        p += __shfl_xor(p, 8);
        p += __shfl_xor(p, 16);
        p += __shfl_xor(p, 32);
        if (e < MAXDEG && lane < H) ssm[wid][e * 4 + lane] = p;
        float mn = fmaxf(m, p);
        z = z * __expf(m - mn) + __expf(p - mn);
        m = mn;
    }

    const float rz = 1.f / z;
    const int dl4 = dl * 4;
    for (int f = lane; f < dl4; f += 64)
        ssm[wid][f] = __expf(ssm[wid][f] - m) * rz;

    float acc0 = 0.f, acc1 = 0.f;
    int e = 0;
    for (; e + 4 <= dl; e += 4) {
        int c0 = cm[wid][e], c1 = cm[wid][e + 1];
        int c2 = cm[wid][e + 2], c3 = cm[wid][e + 3];
        float a0 = ssm[wid][e * 4 + h],       a1 = ssm[wid][(e + 1) * 4 + h];
        float a2 = ssm[wid][(e + 2) * 4 + h], a3 = ssm[wid][(e + 3) * 4 + h];
        const float* v0 = v + (size_t)c0 * D;
        const float* v1 = v + (size_t)c1 * D;
        const float* v2 = v + (size_t)c2 * D;
        const float* v3 = v + (size_t)c3 * D;
        float p00 = v0[lane],      p10 = v1[lane],      p20 = v2[lane],      p30 = v3[lane];
        float p01 = v0[lane + 64], p11 = v1[lane + 64], p21 = v2[lane + 64], p31 = v3[lane + 64];
        acc0 += a0 * p00 + a1 * p10 + a2 * p20 + a3 * p30;
        acc1 += a0 * p01 + a1 * p11 + a2 * p21 + a3 * p31;
    }
    for (; e < dl; ++e) {
        int c = cm[wid][e];
        float a = ssm[wid][e * 4 + h];
        acc0 += a * v[(size_t)c * D + lane];
        acc1 += a * v[(size_t)c * D + lane + 64];
    }
    for (int e2 = MAXDEG; e2 < deg; ++e2) {
        int c = col[e0 + e2];
        const float* kr = k + (size_t)c * D;
        float p = qa * kr[lane] + qb * kr[lane + 64];
        p += __shfl_xor(p, 4);
        p += __shfl_xor(p, 8);
        p += __shfl_xor(p, 16);
        p += __shfl_xor(p, 32);
        float a = __expf(p - m) * rz;
        acc0 += a * v[(size_t)c * D + lane];
        acc1 += a * v[(size_t)c * D + lane + 64];
    }

    y[(size_t)node * D + lane]      = acc0;
    y[(size_t)node * D + lane + 64] = acc1;
}

// ---------------------------------------------------------------------------
extern "C" void kernel_launch(void* const* d_in, const int* in_sizes, int n_in,
                              void* d_out, int out_size, void* d_ws, size_t ws_size,
                              hipStream_t stream)
{
    const float* x   = (const float*)d_in[0];
    const int*   row = (const int*)  d_in[1];
    const int*   col = (const int*)  d_in[2];
    const float* Wq  = (const float*)d_in[3];
    const float* bq  = (const float*)d_in[4];
    const float* Wk  = (const float*)d_in[5];
    const float* bk  = (const float*)d_in[6];
    const float* Wv  = (const float*)d_in[7];
    const float* bv  = (const float*)d_in[8];
    const float* Wo  = (const float*)d_in[9];
    const float* bo  = (const float*)d_in[10];
    float* out = (float*)d_out;

    const int n = in_sizes[0] / D;   // 100000
    const int e = in_sizes[1];       // 800000
    const size_t ND = (size_t)n * D;

    // Workspace layout (phase-aliased):
    //   [0,   ND)  : q  (QKV+edge)      -> yh/yl (out-proj phase)
    //   [ND, 2ND)  : k
    //   [2ND,3ND)  : v
    //   [3ND,4ND)  : xh/xl (QKV phase)  -> y (edge output / out-proj input)
    //   [4ND, ...) : wh (4*D*D u16), wl (4*D*D u16), row_start (n+1 ints)
    float* ws = (float*)d_ws;
    float* q = ws;
    float* k = ws + ND;
    float* v = ws + 2 * ND;
    float* y = ws + 3 * ND;
    unsigned short* xh = (unsigned short*)(ws + 3 * ND);
    unsigned short* xl = xh + ND;
    unsigned short* yh = (unsigned short*)ws;
    unsigned short* yl = yh + ND;
    unsigned short* wh = (unsigned short*)(ws + 4 * ND);
    unsigned short* wl = wh + 4 * D * D;
    int* row_start = (int*)(wl + 4 * D * D);

    const int n4 = (int)(ND / 4);
    const int cvt_grid = (n4 + 255) / 256;
    const int gemm_gx = (n + 63) / 64;

    convert_w<<<(D * D + 255) / 256, 256, 0, stream>>>(Wq, Wk, Wv, Wo, wh, wl);
    convert_split<<<cvt_grid, 256, 0, stream>>>(x, xh, xl, n4);

    // fused QKV: blockIdx.y = {q,k,v}; q scaled by 1/sqrt(H) = 0.5
    gemm_mfma<<<dim3(gemm_gx, 3), 256, 0, stream>>>(
        xh, xl, wh, wl, bq, bk, bv, q, k, v, 0.5f, n);

    build_row_start<<<(n + 1 + 255) / 256, 256, 0, stream>>>(row, row_start, n, e);

    edge_attn<<<(n + WPB - 1) / WPB, WPB * 64, 0, stream>>>(
        row_start, q, k, v, col, y, n);

    convert_split<<<cvt_grid, 256, 0, stream>>>(y, yh, yl, n4);

    // output projection: weight set 3 (Wo), single y-grid
    gemm_mfma<<<dim3(gemm_gx, 1), 256, 0, stream>>>(
        yh, yl, wh + 3 * D * D, wl + 3 * D * D,
        bo, bo, bo, out, out, out, 1.0f, n);
}

// Round 5
// 446.812 us; speedup vs baseline: 1.0922x; 1.0922x over previous
//
#include <hip/hip_runtime.h>
#include <hip/hip_bf16.h>
#include <hip/hip_fp16.h>
#include <math.h>

#define D 128
#define H 4

typedef __attribute__((ext_vector_type(8))) short bf16x8;
typedef __attribute__((ext_vector_type(4))) float f32x4;

// ---------------------------------------------------------------------------
// fp32 -> bf16 split helpers
// ---------------------------------------------------------------------------
__device__ __forceinline__ unsigned short f32_to_bf16_rne(float f) {
    union { float f; unsigned u; } c; c.f = f;
    unsigned u = c.u;
    return (unsigned short)((u + 0x7FFFu + ((u >> 16) & 1u)) >> 16);
}
__device__ __forceinline__ float bf16_to_f32(unsigned short h) {
    union { unsigned u; float f; } c; c.u = ((unsigned)h) << 16;
    return c.f;
}

// ---------------------------------------------------------------------------
// Split fp32 array into bf16 hi + bf16 residual(lo). float4-vectorized.
// ---------------------------------------------------------------------------
__global__ __launch_bounds__(256) void convert_split(
    const float* __restrict__ in, unsigned short* __restrict__ hi,
    unsigned short* __restrict__ lo, int n4)
{
    int i = blockIdx.x * blockDim.x + threadIdx.x;
    if (i >= n4) return;
    float4 v = ((const float4*)in)[i];
    ushort4 h, l;
    h.x = f32_to_bf16_rne(v.x); l.x = f32_to_bf16_rne(v.x - bf16_to_f32(h.x));
    h.y = f32_to_bf16_rne(v.y); l.y = f32_to_bf16_rne(v.y - bf16_to_f32(h.y));
    h.z = f32_to_bf16_rne(v.z); l.z = f32_to_bf16_rne(v.z - bf16_to_f32(h.z));
    h.w = f32_to_bf16_rne(v.w); l.w = f32_to_bf16_rne(v.w - bf16_to_f32(h.w));
    ((ushort4*)hi)[i] = h;
    ((ushort4*)lo)[i] = l;
}

// Split the four 128x128 weight matrices into one packed hi/lo pair.
__global__ __launch_bounds__(256) void convert_w(
    const float* __restrict__ Wq, const float* __restrict__ Wk,
    const float* __restrict__ Wv, const float* __restrict__ Wo,
    unsigned short* __restrict__ wh, unsigned short* __restrict__ wl)
{
    int i = blockIdx.x * blockDim.x + threadIdx.x;
    if (i >= D * D) return;
    const float* Ws[4] = {Wq, Wk, Wv, Wo};
#pragma unroll
    for (int m = 0; m < 4; ++m) {
        float f = Ws[m][i];
        unsigned short h = f32_to_bf16_rne(f);
        wh[m * D * D + i] = h;
        wl[m * D * D + i] = f32_to_bf16_rne(f - bf16_to_f32(h));
    }
}

// ===========================================================================
// Split-precision MFMA GEMM, W LDS-resident, persistent m-loop, A dbuf.
//   out[m,c] = (sum_k x[m,k]*W[c,k] + b[c]) * scale
// x ~ xh+xl, W ~ wh+wl (bf16); xh*wh + xl*wh + xh*wl in fp32 acc.
// Block = 512 thr (8 waves); W (hi+lo) staged once into exactly 64 KB LDS
// with XOR-swizzled 8-short chunks (2-way bank aliasing only -> free).
// Each wave owns 16 rows per iteration, strides by gridDim.x*128.
// A fragments double-buffered. sel = blockIdx.y picks weight/bias/out;
// halfmask bit -> fp16 output (for k/v), else fp32 (*scale).
// ===========================================================================
__global__ __launch_bounds__(512) void gemm_mfma(
    const unsigned short* __restrict__ xh, const unsigned short* __restrict__ xl,
    const unsigned short* __restrict__ whAll, const unsigned short* __restrict__ wlAll,
    const float* __restrict__ b0, const float* __restrict__ b1,
    const float* __restrict__ b2,
    void* __restrict__ o0, void* __restrict__ o1, void* __restrict__ o2,
    float scale0, int n, int wbase, int halfmask)
{
    __shared__ unsigned short Bh[128 * 128];   // 32 KB
    __shared__ unsigned short Bl[128 * 128];   // 32 KB

    const int sel = blockIdx.y;
    const unsigned short* wh = whAll + (size_t)(wbase + sel) * D * D;
    const unsigned short* wl = wlAll + (size_t)(wbase + sel) * D * D;
    const float* bias = (sel == 0) ? b0 : (sel == 1 ? b1 : b2);
    void* out        = (sel == 0) ? o0 : (sel == 1 ? o1 : o2);
    const float scale = (sel == 0) ? scale0 : 1.0f;
    const bool halfOut = (halfmask >> sel) & 1;

    // ---- stage W into LDS, XOR-swizzled 8-short chunks ----
    for (int i = threadIdx.x; i < 128 * 16; i += 512) {
        int r = i >> 4, c8 = i & 15;
        int cs = (c8 ^ (r & 15)) * 8;
        *(bf16x8*)&Bh[r * 128 + cs] = *(const bf16x8*)(wh + (size_t)r * D + c8 * 8);
        *(bf16x8*)&Bl[r * 128 + cs] = *(const bf16x8*)(wl + (size_t)r * D + c8 * 8);
    }
    __syncthreads();

    const int wid  = threadIdx.x >> 6;
    const int lane = threadIdx.x & 63;
    const int quad = lane >> 4;
    const int l16  = lane & 15;
    const int mstride = gridDim.x * 128;

    bf16x8 cah[4], cal[4], nah[4], nal[4];
    int m0 = blockIdx.x * 128 + wid * 16;

    if (m0 < n) {
        int ar = m0 + l16; if (ar > n - 1) ar = n - 1;
        const unsigned short* ph = xh + (size_t)ar * D + quad * 8;
        const unsigned short* pl = xl + (size_t)ar * D + quad * 8;
#pragma unroll
        for (int kc = 0; kc < 4; ++kc) {
            cah[kc] = *(const bf16x8*)(ph + kc * 32);
            cal[kc] = *(const bf16x8*)(pl + kc * 32);
        }
    }

    for (; m0 < n; m0 += mstride) {
        const int m1 = m0 + mstride;
        if (m1 < n) {   // prefetch next tile's A fragments
            int ar = m1 + l16; if (ar > n - 1) ar = n - 1;
            const unsigned short* ph = xh + (size_t)ar * D + quad * 8;
            const unsigned short* pl = xl + (size_t)ar * D + quad * 8;
#pragma unroll
            for (int kc = 0; kc < 4; ++kc) {
                nah[kc] = *(const bf16x8*)(ph + kc * 32);
                nal[kc] = *(const bf16x8*)(pl + kc * 32);
            }
        }

#pragma unroll
        for (int nt = 0; nt < 8; ++nt) {
            f32x4 acc = {0.f, 0.f, 0.f, 0.f};
#pragma unroll
            for (int kc = 0; kc < 4; ++kc) {
                const int rB = nt * 16 + l16;
                const int cs = ((quad + 4 * kc) ^ l16) * 8;
                bf16x8 bh = *(const bf16x8*)&Bh[rB * 128 + cs];
                bf16x8 bl = *(const bf16x8*)&Bl[rB * 128 + cs];
                acc = __builtin_amdgcn_mfma_f32_16x16x32_bf16(cah[kc], bh, acc, 0, 0, 0);
                acc = __builtin_amdgcn_mfma_f32_16x16x32_bf16(cal[kc], bh, acc, 0, 0, 0);
                acc = __builtin_amdgcn_mfma_f32_16x16x32_bf16(cah[kc], bl, acc, 0, 0, 0);
            }
            const int colg = nt * 16 + l16;
            const float bv = bias[colg];
            if (halfOut) {
                __half* oph = (__half*)out;
#pragma unroll
                for (int r = 0; r < 4; ++r) {
                    int rowg = m0 + quad * 4 + r;
                    if (rowg < n)
                        oph[(size_t)rowg * D + colg] = __float2half(acc[r] + bv);
                }
            } else {
                float* opf = (float*)out;
#pragma unroll
                for (int r = 0; r < 4; ++r) {
                    int rowg = m0 + quad * 4 + r;
                    if (rowg < n)
                        opf[(size_t)rowg * D + colg] = (acc[r] + bv) * scale;
                }
            }
        }

        if (m1 < n) {
#pragma unroll
            for (int kc = 0; kc < 4; ++kc) { cah[kc] = nah[kc]; cal[kc] = nal[kc]; }
        }
    }
}

// ---------------------------------------------------------------------------
// row_start[i] = first edge index e with row[e] >= i  (row is sorted)
// ---------------------------------------------------------------------------
__global__ void build_row_start(const int* __restrict__ row,
                                int* __restrict__ row_start, int n, int e)
{
    int i = blockIdx.x * blockDim.x + threadIdx.x;
    if (i > n) return;
    int lo = 0, hi = e;
    while (lo < hi) {
        int mid = (lo + hi) >> 1;
        if (row[mid] < i) lo = mid + 1; else hi = mid;
    }
    row_start[i] = lo;
}

// ===========================================================================
// Fused edge phase: SDDMM + segment-softmax + SPMM, one WAVE per node.
// k, v read as fp16 (half the gather bytes); y written directly as
// bf16 hi/lo split (feeds the MFMA out-projection, kills a convert pass).
// ===========================================================================
#define MAXDEG 64
#define WPB 4

__global__ __launch_bounds__(WPB * 64) void edge_attn(
    const int* __restrict__ row_start,
    const float* __restrict__ q, const __half* __restrict__ k,
    const __half* __restrict__ v, const int* __restrict__ col,
    unsigned short* __restrict__ yh, unsigned short* __restrict__ yl, int n)
{
    __shared__ float ssm[WPB][MAXDEG * H];
    __shared__ int   cm[WPB][MAXDEG];

    const int wid  = threadIdx.x >> 6;
    const int lane = threadIdx.x & 63;
    const int node = blockIdx.x * WPB + wid;
    if (node >= n) return;

    const int e0  = row_start[node];
    const int deg = row_start[node + 1] - e0;
    const int h   = lane & 3;
    const int dl  = deg < MAXDEG ? deg : MAXDEG;

    const float qa = q[(size_t)node * D + lane];
    const float qb = q[(size_t)node * D + lane + 64];

    for (int i = lane; i < dl; i += 64) cm[wid][i] = col[e0 + i];

    float m = -INFINITY, z = 0.f;
    __half kA = __float2half(0.f), kB = kA;
    if (deg > 0) {
        int c0 = cm[wid][0];
        kA = k[(size_t)c0 * D + lane];
        kB = k[(size_t)c0 * D + lane + 64];
    }
    for (int e = 0; e < deg; ++e) {
        float cA = __half2float(kA), cB = __half2float(kB);
        if (e + 1 < deg) {
            int cn = (e + 1 < MAXDEG) ? cm[wid][e + 1] : col[e0 + e + 1];
            kA = k[(size_t)cn * D + lane];
            kB = k[(size_t)cn * D + lane + 64];
        }
        float p = qa * cA + qb * cB;
        p += __shfl_xor(p, 4);
        p += __shfl_xor(p, 8);
        p += __shfl_xor(p, 16);
        p += __shfl_xor(p, 32);
        if (e < MAXDEG && lane < H) ssm[wid][e * 4 + lane] = p;
        float mn = fmaxf(m, p);
        z = z * __expf(m - mn) + __expf(p - mn);
        m = mn;
    }

    const float rz = 1.f / z;
    const int dl4 = dl * 4;
    for (int f = lane; f < dl4; f += 64)
        ssm[wid][f] = __expf(ssm[wid][f] - m) * rz;

    float acc0 = 0.f, acc1 = 0.f;
    int e = 0;
    for (; e + 4 <= dl; e += 4) {
        int c0 = cm[wid][e], c1 = cm[wid][e + 1];
        int c2 = cm[wid][e + 2], c3 = cm[wid][e + 3];
        float a0 = ssm[wid][e * 4 + h],       a1 = ssm[wid][(e + 1) * 4 + h];
        float a2 = ssm[wid][(e + 2) * 4 + h], a3 = ssm[wid][(e + 3) * 4 + h];
        const __half* v0 = v + (size_t)c0 * D;
        const __half* v1 = v + (size_t)c1 * D;
        const __half* v2 = v + (size_t)c2 * D;
        const __half* v3 = v + (size_t)c3 * D;
        float p00 = __half2float(v0[lane]),      p10 = __half2float(v1[lane]);
        float p20 = __half2float(v2[lane]),      p30 = __half2float(v3[lane]);
        float p01 = __half2float(v0[lane + 64]), p11 = __half2float(v1[lane + 64]);
        float p21 = __half2float(v2[lane + 64]), p31 = __half2float(v3[lane + 64]);
        acc0 += a0 * p00 + a1 * p10 + a2 * p20 + a3 * p30;
        acc1 += a0 * p01 + a1 * p11 + a2 * p21 + a3 * p31;
    }
    for (; e < dl; ++e) {
        int c = cm[wid][e];
        float a = ssm[wid][e * 4 + h];
        acc0 += a * __half2float(v[(size_t)c * D + lane]);
        acc1 += a * __half2float(v[(size_t)c * D + lane + 64]);
    }
    for (int e2 = MAXDEG; e2 < deg; ++e2) {
        int c = col[e0 + e2];
        const __half* kr = k + (size_t)c * D;
        float p = qa * __half2float(kr[lane]) + qb * __half2float(kr[lane + 64]);
        p += __shfl_xor(p, 4);
        p += __shfl_xor(p, 8);
        p += __shfl_xor(p, 16);
        p += __shfl_xor(p, 32);
        float a = __expf(p - m) * rz;
        acc0 += a * __half2float(v[(size_t)c * D + lane]);
        acc1 += a * __half2float(v[(size_t)c * D + lane + 64]);
    }

    // epilogue: bf16 hi/lo split of y (feeds out-projection MFMA GEMM)
    unsigned short h0 = f32_to_bf16_rne(acc0);
    unsigned short h1 = f32_to_bf16_rne(acc1);
    yh[(size_t)node * D + lane]      = h0;
    yh[(size_t)node * D + lane + 64] = h1;
    yl[(size_t)node * D + lane]      = f32_to_bf16_rne(acc0 - bf16_to_f32(h0));
    yl[(size_t)node * D + lane + 64] = f32_to_bf16_rne(acc1 - bf16_to_f32(h1));
}

// ---------------------------------------------------------------------------
extern "C" void kernel_launch(void* const* d_in, const int* in_sizes, int n_in,
                              void* d_out, int out_size, void* d_ws, size_t ws_size,
                              hipStream_t stream)
{
    const float* x   = (const float*)d_in[0];
    const int*   row = (const int*)  d_in[1];
    const int*   col = (const int*)  d_in[2];
    const float* Wq  = (const float*)d_in[3];
    const float* bq  = (const float*)d_in[4];
    const float* Wk  = (const float*)d_in[5];
    const float* bk  = (const float*)d_in[6];
    const float* Wv  = (const float*)d_in[7];
    const float* bv  = (const float*)d_in[8];
    const float* Wo  = (const float*)d_in[9];
    const float* bo  = (const float*)d_in[10];
    float* out = (float*)d_out;

    const int n = in_sizes[0] / D;   // 100000
    const int e = in_sizes[1];       // 800000
    const size_t ND = (size_t)n * D;

    // Workspace (floats as unit):
    //   [0,    ND)   q  fp32
    //   [ND,  1.5ND) kh fp16
    //   [1.5ND,2ND)  vh fp16
    //   [2ND, 2.5ND) xh bf16   (aliased: yh after QKV phase)
    //   [2.5ND,3ND)  xl bf16   (aliased: yl)
    //   [3ND, ...)   wh, wl (4*D*D shorts each), row_start
    float* ws = (float*)d_ws;
    float*  q  = ws;
    __half* kh = (__half*)(ws + ND);
    __half* vh = kh + ND;
    unsigned short* xh = (unsigned short*)(ws + 2 * ND);
    unsigned short* xl = xh + ND;
    unsigned short* yh = xh;   // alias (x split dead after QKV GEMM)
    unsigned short* yl = xl;
    unsigned short* wh = (unsigned short*)(ws + 3 * ND);
    unsigned short* wl = wh + 4 * D * D;
    int* row_start = (int*)(wl + 4 * D * D);

    const int n4 = (int)(ND / 4);

    convert_w<<<(D * D + 255) / 256, 256, 0, stream>>>(Wq, Wk, Wv, Wo, wh, wl);
    convert_split<<<(n4 + 255) / 256, 256, 0, stream>>>(x, xh, xl, n4);

    // fused QKV: sel 0 -> q fp32 (*0.5), sel 1 -> k fp16, sel 2 -> v fp16
    gemm_mfma<<<dim3(170, 3), 512, 0, stream>>>(
        xh, xl, wh, wl, bq, bk, bv,
        (void*)q, (void*)kh, (void*)vh, 0.5f, n, 0, /*halfmask=*/6);

    build_row_start<<<(n + 1 + 255) / 256, 256, 0, stream>>>(row, row_start, n, e);

    edge_attn<<<(n + WPB - 1) / WPB, WPB * 64, 0, stream>>>(
        row_start, q, kh, vh, col, yh, yl, n);

    // output projection: weight slot 3 (Wo), fp32 out
    gemm_mfma<<<dim3(512, 1), 512, 0, stream>>>(
        yh, yl, wh, wl, bo, bo, bo,
        (void*)out, (void*)out, (void*)out, 1.0f, n, 3, /*halfmask=*/0);
}